// Round 1
// baseline (389.105 us; speedup 1.0000x reference)
//
#include <hip/hip_runtime.h>
#include <cmath>

#define NPTS 4096
#define NPOINT 204   // int(4096 * 0.05)
#define NPCT 5
#define MAXNS 409    // int(4096 * 0.10)

struct LossParams {
    int   nsample[NPCT];
    float r2[NPCT];
    float wscale[NPCT];   // (p*100)^2 / (B*NPOINT*NPCT)
    float expect_len;
};

// ---------------------------------------------------------------------------
// Kernel 1: furthest point sampling, one block per batch.
// Matches jnp argmax-first-occurrence tie semantics; distance computed with
// fp contraction OFF in ((dx^2+dy^2)+dz^2) order to match the numpy reference.
// ---------------------------------------------------------------------------
__global__ __launch_bounds__(256) void fps_kernel(const float* __restrict__ pcd,
                                                  int* __restrict__ fps_idx) {
#pragma clang fp contract(off)
    __shared__ float px[NPTS], py[NPTS], pz[NPTS];
    __shared__ float s_rv[4];
    __shared__ int   s_ri[4];
    __shared__ int   s_last;

    const int b = blockIdx.x;
    const int t = threadIdx.x;
    const float* base = pcd + (size_t)b * NPTS * 3;

    float x[16], y[16], z[16], dist[16];
    #pragma unroll
    for (int k = 0; k < 16; ++k) {
        int n = k * 256 + t;
        float vx = base[3 * n + 0];
        float vy = base[3 * n + 1];
        float vz = base[3 * n + 2];
        px[n] = vx; py[n] = vy; pz[n] = vz;
        x[k] = vx; y[k] = vy; z[k] = vz;
        dist[k] = 1e10f;
    }
    int* out = fps_idx + b * NPOINT;
    if (t == 0) { out[0] = 0; s_last = 0; }
    __syncthreads();

    int last = 0;
    for (int it = 1; it < NPOINT; ++it) {
        float cx = px[last], cy = py[last], cz = pz[last];
        float best = -1.0f; int bidx = 0;
        #pragma unroll
        for (int k = 0; k < 16; ++k) {
            float dx = x[k] - cx, dy = y[k] - cy, dz = z[k] - cz;
            float d  = (dx * dx + dy * dy) + dz * dz;
            float dk = fminf(dist[k], d);
            dist[k] = dk;
            if (dk > best) { best = dk; bidx = k * 256 + t; }  // ascending n -> keeps earliest on tie
        }
        // wave64 argmax reduce, tie -> smaller index
        #pragma unroll
        for (int off = 32; off; off >>= 1) {
            float v2 = __shfl_down(best, off);
            int   i2 = __shfl_down(bidx, off);
            if (v2 > best || (v2 == best && i2 < bidx)) { best = v2; bidx = i2; }
        }
        const int wave = t >> 6;
        if ((t & 63) == 0) { s_rv[wave] = best; s_ri[wave] = bidx; }
        __syncthreads();
        if (t == 0) {
            float bv = s_rv[0]; int bi = s_ri[0];
            #pragma unroll
            for (int w = 1; w < 4; ++w) {
                float v2 = s_rv[w]; int i2 = s_ri[w];
                if (v2 > bv || (v2 == bv && i2 < bi)) { bv = v2; bi = i2; }
            }
            s_last = bi;
            out[it] = bi;
        }
        __syncthreads();
        last = s_last;
    }
}

// ---------------------------------------------------------------------------
// Kernel 2: per (group, percentage) block: ball query (ordered compaction,
// pn2 pad-with-first semantics) + nearest-neighbor distance + loss term.
// ---------------------------------------------------------------------------
__global__ __launch_bounds__(256) void group_kernel(const float* __restrict__ pcd,
                                                    const int* __restrict__ fps_idx,
                                                    float* __restrict__ out,
                                                    LossParams P) {
    const int pidx = blockIdx.y;
    const int g    = blockIdx.x;           // 0 .. B*NPOINT-1
    const int b    = g / NPOINT;
    const int m    = g - b * NPOINT;
    const int t    = threadIdx.x;
    const int wave = t >> 6, lane = t & 63;

    const int   nsample = P.nsample[pidx];
    const float r2      = P.r2[pidx];

    __shared__ float4 gpts[MAXNS];
    __shared__ int    s_wcnt[4];
    __shared__ int    s_cnt;
    __shared__ float  s_part[4];
    __shared__ float  s_q[3];

    const float* base = pcd + (size_t)b * NPTS * 3;
    if (t == 0) {
        int qi = fps_idx[b * NPOINT + m];
        s_q[0] = base[3 * qi + 0];
        s_q[1] = base[3 * qi + 1];
        s_q[2] = base[3 * qi + 2];
        s_cnt = 0;
    }
    __syncthreads();
    const float qx = s_q[0], qy = s_q[1], qz = s_q[2];

    // ---- Phase A: ball query with ordered compaction into LDS ----
    for (int chunk = 0; chunk < NPTS / 256; ++chunk) {
        int n = chunk * 256 + t;
        float x = base[3 * n + 0];
        float y = base[3 * n + 1];
        float z = base[3 * n + 2];
        float d2;
        {
#pragma clang fp contract(off)
            float dx = qx - x, dy = qy - y, dz = qz - z;
            float a = dx * dx, bb = dy * dy, c = dz * dz;
            d2 = (a + bb) + c;
        }
        bool in = d2 < r2;                      // strict, matches reference
        unsigned long long mask = __ballot(in);
        if (lane == 0) s_wcnt[wave] = __popcll(mask);
        __syncthreads();
        int base_cnt = s_cnt;
        int prefix = 0;
        for (int w = 0; w < wave; ++w) prefix += s_wcnt[w];
        int pos = base_cnt + prefix + __popcll(mask & ((1ull << lane) - 1ull));
        if (in && pos < nsample) gpts[pos] = make_float4(x, y, z, 0.0f);
        __syncthreads();
        if (t == 0) s_cnt = base_cnt + s_wcnt[0] + s_wcnt[1] + s_wcnt[2] + s_wcnt[3];
        __syncthreads();
        if (s_cnt >= nsample) break;            // uniform
    }
    int cv = s_cnt;
    if (cv > nsample) cv = nsample;
    // pad with first found point (always exists: query point itself has d2=0)
    float4 p0 = gpts[0];
    for (int i = cv + t; i < nsample; i += 256) gpts[i] = p0;
    __syncthreads();

    // ---- Phase B: nn distance (min over j != i) + per-group mean ----
    float sum = 0.0f;
    for (int i = t; i < nsample; i += 256) {
        float4 pi = gpts[i];
        float dmin = 1e30f;
        for (int j = 0; j < nsample; ++j) {
            float4 pj = gpts[j];
            float dx = pi.x - pj.x, dy = pi.y - pj.y, dz = pi.z - pj.z;
            float d2 = fmaf(dx, dx, fmaf(dy, dy, dz * dz));
            float cand = (j == i) ? 1e30f : d2;
            dmin = fminf(dmin, cand);
        }
        sum += fabsf(sqrtf(dmin) + 0.1f);
    }
    #pragma unroll
    for (int off = 32; off; off >>= 1) sum += __shfl_down(sum, off);
    if (lane == 0) s_part[wave] = sum;
    __syncthreads();
    if (t == 0) {
        float tot = s_part[0] + s_part[1] + s_part[2] + s_part[3];
        float u  = tot / (float)nsample;
        float du = u - P.expect_len;
        float contrib = du * du / (P.expect_len + 0.1f) * P.wscale[pidx];
        atomicAdd(out, contrib);
    }
}

extern "C" void kernel_launch(void* const* d_in, const int* in_sizes, int n_in,
                              void* d_out, int out_size, void* d_ws, size_t ws_size,
                              hipStream_t stream) {
    const float* pcd = (const float*)d_in[0];
    const int B = in_sizes[0] / (NPTS * 3);   // = 2
    float* out = (float*)d_out;
    int* fps = (int*)d_ws;                    // B*NPOINT ints

    hipMemsetAsync(d_out, 0, sizeof(float), stream);

    fps_kernel<<<dim3(B), dim3(256), 0, stream>>>(pcd, fps);

    LossParams P;
    const double ps[NPCT] = {0.02, 0.04, 0.06, 0.08, 0.10};
    for (int i = 0; i < NPCT; ++i) {
        P.nsample[i] = (int)(NPTS * ps[i]);
        double r = std::sqrt(ps[i] * 1.0);
        P.r2[i] = (float)(r * r);
        double w = (ps[i] * 100.0) * (ps[i] * 100.0);
        P.wscale[i] = (float)(w / (double)(B * NPOINT * NPCT));
    }
    P.expect_len = (float)std::sqrt(3.14159265358979323846 / (double)NPTS);

    dim3 grid(B * NPOINT, NPCT);
    group_kernel<<<grid, dim3(256), 0, stream>>>(pcd, fps, out, P);
}

// Round 2
// 237.980 us; speedup vs baseline: 1.6350x; 1.6350x over previous
//
#include <hip/hip_runtime.h>
#include <cmath>

#define NPTS 4096
#define NPOINT 204   // int(4096 * 0.05)
#define NPCT 5
#define MAXNS 409    // int(4096 * 0.10)

struct LossParams {
    int   nsample[NPCT];
    float r2[NPCT];
    float wscale[NPCT];   // (p*100)^2 / (B*NPOINT*NPCT)
    float expect_len;
};

// ---------------- DPP wave64 reductions (VALU-latency, no LDS) -------------
// row_shr:n = 0x110|n, row_bcast15 = 0x142, row_bcast31 = 0x143.
// For max over nonneg int (float bits of d2>=0): identity 0 via bound_ctrl=1.
// Coverage: shr 1/2/4/8 -> row maxes in lanes 15/31/47/63; bcast15 merges
// row(k) into row(k+1) tail; bcast31 merges lanes0-31 result into 32-63.
// Lane 63 ends with the full-wave reduce.
template <int CTRL>
__device__ __forceinline__ int dpp_imax(int v) {
    int t = __builtin_amdgcn_update_dpp(0, v, CTRL, 0xf, 0xf, true);
    return v > t ? v : t;
}
template <int CTRL>
__device__ __forceinline__ int dpp_imin(int v) {
    int t = __builtin_amdgcn_update_dpp(0x7fffffff, v, CTRL, 0xf, 0xf, false);
    return v < t ? v : t;
}
__device__ __forceinline__ int wave_max_i(int v) {
    v = dpp_imax<0x111>(v); v = dpp_imax<0x112>(v);
    v = dpp_imax<0x114>(v); v = dpp_imax<0x118>(v);
    v = dpp_imax<0x142>(v); v = dpp_imax<0x143>(v);
    return __builtin_amdgcn_readlane(v, 63);
}
__device__ __forceinline__ int wave_min_i(int v) {
    v = dpp_imin<0x111>(v); v = dpp_imin<0x112>(v);
    v = dpp_imin<0x114>(v); v = dpp_imin<0x118>(v);
    v = dpp_imin<0x142>(v); v = dpp_imin<0x143>(v);
    return __builtin_amdgcn_readlane(v, 63);
}

// ---------------------------------------------------------------------------
// Kernel 1: furthest point sampling, one block per batch. 203 serial argmax
// iterations; per-iter chain = dist VALU + 2 DPP reduces + 1 barrier + LDS
// key exchange. Tie semantics: first occurrence (smallest global index),
// distance with fp contract OFF in ((dx^2+dy^2)+dz^2) order (matches ref).
// ---------------------------------------------------------------------------
__global__ __launch_bounds__(256) void fps_kernel(const float* __restrict__ pcd,
                                                  int* __restrict__ fps_idx) {
#pragma clang fp contract(off)
    __shared__ float px[NPTS], py[NPTS], pz[NPTS];
    __shared__ unsigned long long keys[2][4];   // ping-pong: 1 barrier/iter

    const int b = blockIdx.x;
    const int t = threadIdx.x;
    const int wave = t >> 6, lane = t & 63;
    const float* base = pcd + (size_t)b * NPTS * 3;

    float x[16], y[16], z[16], dist[16];
    #pragma unroll
    for (int k = 0; k < 16; ++k) {
        int n = k * 256 + t;
        float vx = base[3 * n + 0];
        float vy = base[3 * n + 1];
        float vz = base[3 * n + 2];
        px[n] = vx; py[n] = vy; pz[n] = vz;
        x[k] = vx; y[k] = vy; z[k] = vz;
        dist[k] = 1e10f;
    }
    int* out = fps_idx + b * NPOINT;
    if (t == 0) out[0] = 0;
    __syncthreads();

    float cx = px[0], cy = py[0], cz = pz[0];
    for (int it = 1; it < NPOINT; ++it) {
        int bestbits = -1, bestidx = 0;
        #pragma unroll
        for (int k = 0; k < 16; ++k) {
            float dx = x[k] - cx, dy = y[k] - cy, dz = z[k] - cz;
            float d  = (dx * dx + dy * dy) + dz * dz;
            float dk = fminf(dist[k], d);
            dist[k] = dk;
            int bits = __float_as_int(dk);       // nonneg: int cmp == float cmp
            if (bits > bestbits) { bestbits = bits; bestidx = k * 256 + t; }
        }
        int wmax = wave_max_i(bestbits);
        int cand = (bestbits == wmax) ? bestidx : 0x7fffffff;
        int widx = wave_min_i(cand);             // smallest index among ties
        if (lane == 0)
            keys[it & 1][wave] =
                ((unsigned long long)(unsigned)wmax << 32) | (unsigned)(~(unsigned)widx);
        __syncthreads();
        unsigned long long k0 = keys[it & 1][0], k1 = keys[it & 1][1];
        unsigned long long k2 = keys[it & 1][2], k3 = keys[it & 1][3];
        unsigned long long ka = k0 > k1 ? k0 : k1;
        unsigned long long kb = k2 > k3 ? k2 : k3;
        unsigned long long kk = ka > kb ? ka : kb;
        int last = (int)(~(unsigned)(kk & 0xFFFFFFFFull));
        cx = px[last]; cy = py[last]; cz = pz[last];
        if (t == 0) out[it] = last;
    }
}

// ---------------------------------------------------------------------------
// Kernel 2: per (group, percentage) block.
// Phase A: 2-barrier ballot compaction — each wave owns a contiguous 1024-pt
// index segment; 16 sub-chunk ballot masks + local prefix stay in SGPRs;
// only wave totals cross waves. Index order preserved (pn2 truncation).
// Phase B: NN distance over REAL points only; pads (duplicates of gpts[0])
// contribute exactly 0.1 each analytically, and point 0's nn is 0 iff npad>0.
// ---------------------------------------------------------------------------
__global__ __launch_bounds__(256) void group_kernel(const float* __restrict__ pcd,
                                                    const int* __restrict__ fps_idx,
                                                    float* __restrict__ out,
                                                    LossParams P) {
    const int pidx = blockIdx.y;
    const int g    = blockIdx.x;           // 0 .. B*NPOINT-1
    const int b    = g / NPOINT;
    const int m    = g - b * NPOINT;
    const int t    = threadIdx.x;
    const int wave = t >> 6, lane = t & 63;

    const int   ns = P.nsample[pidx];
    const float r2 = P.r2[pidx];

    __shared__ float4 gpts[MAXNS + 4];     // +4 sentinel pad for j-unroll
    __shared__ int    s_wtot[4];
    __shared__ float  s_part[4];

    const float* base = pcd + (size_t)b * NPTS * 3;
    int qi = fps_idx[b * NPOINT + m];      // broadcast load (uniform)
    float qx = base[3 * qi + 0], qy = base[3 * qi + 1], qz = base[3 * qi + 2];

    // ---- Phase A pass 1: ballot the wave's 16 sub-chunks of 64 points ----
    unsigned long long msk[16];
    int lbase[16];
    int run = 0;
    #pragma unroll 4
    for (int s = 0; s < 16; ++s) {
        int n = wave * 1024 + s * 64 + lane;
        float x = base[3 * n + 0];
        float y = base[3 * n + 1];
        float z = base[3 * n + 2];
        float d2;
        {
#pragma clang fp contract(off)
            float dx = qx - x, dy = qy - y, dz = qz - z;
            float aa = dx * dx, bb = dy * dy, cc = dz * dz;
            d2 = (aa + bb) + cc;
        }
        msk[s] = __ballot(d2 < r2);        // strict <, matches reference
        lbase[s] = run;
        run += __popcll(msk[s]);
    }
    if (lane == 0) s_wtot[wave] = run;
    __syncthreads();
    int w0 = s_wtot[0], w1 = s_wtot[1], w2 = s_wtot[2], w3 = s_wtot[3];
    int Bw = (wave > 0 ? w0 : 0) + (wave > 1 ? w1 : 0) + (wave > 2 ? w2 : 0);
    int cnt  = w0 + w1 + w2 + w3;
    int cntB = cnt < ns ? cnt : ns;        // real points kept
    const int npad = ns - cntB;

    // ---- Phase A pass 2: ordered compaction into LDS ----
    #pragma unroll 4
    for (int s = 0; s < 16; ++s) {
        int gb = Bw + lbase[s];            // wave-uniform
        if (gb >= ns) break;
        unsigned long long mk = msk[s];
        bool in = (mk >> lane) & 1ull;
        int pos = gb + __popcll(mk & ((1ull << lane) - 1ull));
        if (in && pos < ns) {
            int n = wave * 1024 + s * 64 + lane;
            gpts[pos] = make_float4(base[3 * n], base[3 * n + 1], base[3 * n + 2], 0.0f);
        }
    }
    if (t < 4) gpts[cntB + t] = make_float4(1e6f, 1e6f, 1e6f, 0.0f);  // sentinels
    __syncthreads();

    // ---- Phase B: nn among real points, j unrolled x4 ----
    float sum = 0.0f;
    for (int i = t; i < cntB; i += 256) {
        float4 pi = gpts[i];
        float m0 = 1e30f, m1 = 1e30f, m2 = 1e30f, m3 = 1e30f;
        for (int jt = 0; jt < cntB; jt += 4) {
            float4 a = gpts[jt + 0];
            float4 bb = gpts[jt + 1];
            float4 c = gpts[jt + 2];
            float4 d = gpts[jt + 3];
            float dx, dy, dz, t0, t1, t2, t3;
            dx = pi.x - a.x;  dy = pi.y - a.y;  dz = pi.z - a.z;
            t0 = fmaf(dx, dx, fmaf(dy, dy, dz * dz));
            dx = pi.x - bb.x; dy = pi.y - bb.y; dz = pi.z - bb.z;
            t1 = fmaf(dx, dx, fmaf(dy, dy, dz * dz));
            dx = pi.x - c.x;  dy = pi.y - c.y;  dz = pi.z - c.z;
            t2 = fmaf(dx, dx, fmaf(dy, dy, dz * dz));
            dx = pi.x - d.x;  dy = pi.y - d.y;  dz = pi.z - d.z;
            t3 = fmaf(dx, dx, fmaf(dy, dy, dz * dz));
            m0 = fminf(m0, (jt + 0 == i) ? 1e30f : t0);
            m1 = fminf(m1, (jt + 1 == i) ? 1e30f : t1);
            m2 = fminf(m2, (jt + 2 == i) ? 1e30f : t2);
            m3 = fminf(m3, (jt + 3 == i) ? 1e30f : t3);
        }
        float dmin = fminf(fminf(m0, m1), fminf(m2, m3));
        // pads duplicate gpts[0] => point 0's nn is exactly 0 when npad>0
        if (!(i == 0 && npad > 0)) sum += sqrtf(dmin);
    }
    #pragma unroll
    for (int off = 32; off; off >>= 1) sum += __shfl_down(sum, off);
    if (lane == 0) s_part[wave] = sum;
    __syncthreads();
    if (t == 0) {
        // every entry contributes |nn + 0.1| = nn + 0.1; pads/excluded have nn=0
        float tot = s_part[0] + s_part[1] + s_part[2] + s_part[3] + 0.1f * (float)ns;
        float u  = tot / (float)ns;
        float du = u - P.expect_len;
        float contrib = du * du / (P.expect_len + 0.1f) * P.wscale[pidx];
        atomicAdd(out, contrib);
    }
}

extern "C" void kernel_launch(void* const* d_in, const int* in_sizes, int n_in,
                              void* d_out, int out_size, void* d_ws, size_t ws_size,
                              hipStream_t stream) {
    const float* pcd = (const float*)d_in[0];
    const int B = in_sizes[0] / (NPTS * 3);   // = 2
    float* out = (float*)d_out;
    int* fps = (int*)d_ws;                    // B*NPOINT ints

    hipMemsetAsync(d_out, 0, out_size * sizeof(float), stream);

    fps_kernel<<<dim3(B), dim3(256), 0, stream>>>(pcd, fps);

    LossParams P;
    const double ps[NPCT] = {0.02, 0.04, 0.06, 0.08, 0.10};
    for (int i = 0; i < NPCT; ++i) {
        P.nsample[i] = (int)(NPTS * ps[i]);
        double r = std::sqrt(ps[i] * 1.0);
        P.r2[i] = (float)(r * r);
        double w = (ps[i] * 100.0) * (ps[i] * 100.0);
        P.wscale[i] = (float)(w / (double)(B * NPOINT * NPCT));
    }
    P.expect_len = (float)std::sqrt(3.14159265358979323846 / (double)NPTS);

    dim3 grid(B * NPOINT, NPCT);
    group_kernel<<<grid, dim3(256), 0, stream>>>(pcd, fps, out, P);
}